// Round 1
// baseline (2095.211 us; speedup 1.0000x reference)
//
#include <hip/hip_runtime.h>
#include <hip/hip_bf16.h>

// ---------------------------------------------------------------------------
// TGN temporal attention layer, MI355X.
// Shapes: B=8192, K=20, D=DT=DE=256, H=2, DQ=512, DK=768, dh=256.
// Strategy:
//   prep:  pack Wk|Wv -> bf16 k-major [96][1024][8]; WoW1 = Wo @ W1[0:512];
//          srcq_const = cos(time_b) @ Wq[256:512]
//   kB  :  q = src_feat @ Wq[0:256] + srcq_const ; srcf -> ws   (f32 VALU)
//   kC  :  fused gather + KV GEMM (bf16 MFMA 16x16x32) + attention -> ctx
//   kD  :  out = relu(ctx@WoW1 + srcf@W1[512:768] + b1) @ W2 + b2 (f32 VALU)
// ws layout (bytes): WkvP 0 .. 1572864 ; WoW1 .. 2097152 ; srcq .. 2099200 ;
//   q .. 18876416 ; srcf .. 27265024 ; ctx .. 44042240   (needs ~42 MB ws)
// ---------------------------------------------------------------------------

typedef __attribute__((ext_vector_type(4))) float f32x4;
typedef __attribute__((ext_vector_type(8))) short bf16x8;
typedef __attribute__((ext_vector_type(8))) unsigned short u16x8;

#define NB 8192
#define KN 20
#define TB 4
#define RR (TB * KN)   // 80 kv rows per block

__device__ __forceinline__ unsigned short f2bf(float f) {
  unsigned u = __builtin_bit_cast(unsigned, f);
  u += 0x7FFFu + ((u >> 16) & 1u);          // RNE
  return (unsigned short)(u >> 16);
}
__device__ __forceinline__ float bf2f(unsigned short h) {
  return __builtin_bit_cast(float, ((unsigned)h) << 16);
}
__device__ __forceinline__ float4 f4add(float4 a, float4 b) {
  return make_float4(a.x + b.x, a.y + b.y, a.z + b.z, a.w + b.w);
}

// --------------------------- prep kernels ----------------------------------

// WkvP[kg][n][j] = bf16( (n<512 ? Wk : Wv)[kg*8+j][n&511] ), kg<96, n<1024, j<8
__global__ void k_pack_wkv(const float* __restrict__ Wk,
                           const float* __restrict__ Wv,
                           unsigned short* __restrict__ WkvP) {
  int idx = blockIdx.x * 256 + threadIdx.x;
  if (idx >= 96 * 1024 * 8) return;
  int j = idx & 7, n = (idx >> 3) & 1023, kg = idx >> 13;
  int kk = kg * 8 + j;
  float v = (n < 512) ? Wk[kk * 512 + n] : Wv[kk * 512 + (n - 512)];
  WkvP[idx] = f2bf(v);
}

// WoW1[i][j] = sum_c Wo[i][c] * W1[c][j], i<512, j<256
__global__ void k_wow1(const float* __restrict__ Wo,
                       const float* __restrict__ W1,
                       float* __restrict__ WoW1) {
  int t = blockIdx.x * 256 + threadIdx.x;
  if (t >= 512 * 256) return;
  int i = t >> 8, j = t & 255;
  float acc = 0.f;
  for (int c = 0; c < 512; ++c) acc += Wo[i * 512 + c] * W1[c * 256 + j];
  WoW1[i * 256 + j] = acc;
}

// srcq[n] = sum_c cos(time_b[c]) * Wq[(256+c)*512 + n], n<512
__global__ void k_srcq(const float* __restrict__ time_b,
                       const float* __restrict__ Wq,
                       float* __restrict__ srcq) {
  int n = blockIdx.x * 256 + threadIdx.x;
  if (n >= 512) return;
  float acc = 0.f;
  for (int c = 0; c < 256; ++c) acc += cosf(time_b[c]) * Wq[(256 + c) * 512 + n];
  srcq[n] = acc;
}

// --------------------------- q projection ----------------------------------
// 8 rows / block of 256 threads. q = srcf @ Wq[0:256,:] + srcq ; srcf -> ws
__global__ __launch_bounds__(256) void k_qproj(
    const int* __restrict__ src_nodes, const float* __restrict__ memory,
    const float* __restrict__ node_table, const float* __restrict__ Wq,
    const float* __restrict__ srcq, float* __restrict__ q_out,
    float* __restrict__ srcf_out) {
  __shared__ float sf[8][256];
  __shared__ int sid[8];
  const int tid = threadIdx.x;
  const int r0 = blockIdx.x * 8;
  if (tid < 8) sid[tid] = src_nodes[r0 + tid];
  __syncthreads();
  for (int i = tid; i < 8 * 64; i += 256) {
    int r = i >> 6, c4 = (i & 63) << 2;
    int n = sid[r];
    float4 m0 = *(const float4*)(memory + n * 256 + c4);
    float4 t0 = *(const float4*)(node_table + n * 256 + c4);
    float4 s = f4add(m0, t0);
    *(float4*)(&sf[r][c4]) = s;
    *(float4*)(srcf_out + (r0 + r) * 256 + c4) = s;
  }
  __syncthreads();
  const int r = tid >> 5, nb = (tid & 31) << 4;  // 16 outputs each
  float acc[16];
#pragma unroll
  for (int j = 0; j < 16; ++j) acc[j] = srcq[nb + j];
  for (int c = 0; c < 256; ++c) {
    float s = sf[r][c];
#pragma unroll
    for (int j4 = 0; j4 < 4; ++j4) {
      float4 w = *(const float4*)(Wq + c * 512 + nb + j4 * 4);
      acc[j4 * 4 + 0] += s * w.x;
      acc[j4 * 4 + 1] += s * w.y;
      acc[j4 * 4 + 2] += s * w.z;
      acc[j4 * 4 + 3] += s * w.w;
    }
  }
#pragma unroll
  for (int j4 = 0; j4 < 4; ++j4)
    *(float4*)(q_out + (r0 + r) * 512 + nb + j4 * 4) =
        make_float4(acc[j4 * 4 + 0], acc[j4 * 4 + 1], acc[j4 * 4 + 2], acc[j4 * 4 + 3]);
}

// --------------------------- fused attention -------------------------------
// Block: 512 threads (8 waves), TB=4 src rows -> RR=80 kv rows.
// GEMM [80,768]@[768,1024] in 2 phases of 512 cols (K then V).
// Wave w owns cols w*64..w*64+63 of the 512-col phase; 5x4 16x16 frags.
__global__ __launch_bounds__(512, 2) void k_attn(
    const int* __restrict__ neighbors, const int* __restrict__ edge_idxs,
    const float* __restrict__ edge_times, const float* __restrict__ timestamps,
    const float* __restrict__ memory, const float* __restrict__ node_table,
    const float* __restrict__ edge_features, const float* __restrict__ time_w,
    const float* __restrict__ time_b, const unsigned short* __restrict__ WkvP,
    const float* __restrict__ q_ws, float* __restrict__ ctx_ws) {
  union UShape {
    struct { unsigned short As[RR * 64]; unsigned short Bs[8 * 512 * 8]; } s;  // 75776 B
    unsigned short dump[RR * 516];                                             // 82560 B
  };
  __shared__ __align__(16) UShape u;
  __shared__ float q_lds[TB][512];
  __shared__ float tw_s[256], tb_s[256];
  __shared__ int nbr_s[RR];
  __shared__ int eidx_s[RR];
  __shared__ float dl_s[RR];
  __shared__ float scores[2][RR];
  __shared__ float attnw[2][RR];
  __shared__ int invalid_s[TB];

  const int tid = threadIdx.x;
  const int wid = tid >> 6;
  const int lane = tid & 63;
  const int lr = lane & 15, lg = lane >> 4;
  const int gb0 = blockIdx.x * TB;

  for (int i = tid; i < 256; i += 512) { tw_s[i] = time_w[i]; tb_s[i] = time_b[i]; }
  for (int i = tid; i < RR; i += 512) {
    nbr_s[i] = neighbors[gb0 * KN + i];
    eidx_s[i] = edge_idxs[gb0 * KN + i];
    dl_s[i] = timestamps[gb0 + i / KN] - edge_times[gb0 * KN + i];
  }
  for (int i = tid; i < TB * 128; i += 512) {
    int r = i >> 7, c4 = (i & 127) << 2;
    *(float4*)(&q_lds[r][c4]) = *(const float4*)(q_ws + (gb0 + r) * 512 + c4);
  }
  __syncthreads();
  if (tid < TB) {
    int inv = 1;
    for (int kk = 0; kk < KN; ++kk) inv &= (nbr_s[tid * KN + kk] == 0);
    invalid_s[tid] = inv;
  }

  char* Asb = (char*)u.s.As;
  char* Bsb = (char*)u.s.Bs;

  for (int p = 0; p < 2; ++p) {
    f32x4 acc[5][4];
#pragma unroll
    for (int a = 0; a < 5; ++a)
#pragma unroll
      for (int b = 0; b < 4; ++b) acc[a][b] = f32x4{0.f, 0.f, 0.f, 0.f};

    for (int kc = 0; kc < 12; ++kc) {
      __syncthreads();
      // ---- stage A: 80 rows x 64 cols bf16, XOR-swizzled (row&7)<<4 ----
      for (int i = tid; i < RR * 8; i += 512) {
        int r = i >> 3, c8 = i & 7;
        int g0 = kc * 64 + c8 * 8;
        float v[8];
        if (g0 < 256) {
          int n = nbr_s[r];
          float4 m0 = *(const float4*)(memory + n * 256 + g0);
          float4 m1 = *(const float4*)(memory + n * 256 + g0 + 4);
          float4 t0 = *(const float4*)(node_table + n * 256 + g0);
          float4 t1 = *(const float4*)(node_table + n * 256 + g0 + 4);
          v[0] = m0.x + t0.x; v[1] = m0.y + t0.y; v[2] = m0.z + t0.z; v[3] = m0.w + t0.w;
          v[4] = m1.x + t1.x; v[5] = m1.y + t1.y; v[6] = m1.z + t1.z; v[7] = m1.w + t1.w;
        } else if (g0 < 512) {
          int c = g0 - 256;
          float d = dl_s[r];
#pragma unroll
          for (int j = 0; j < 8; ++j) v[j] = __cosf(d * tw_s[c + j] + tb_s[c + j]);
        } else {
          int c = g0 - 512;
          int e = eidx_s[r];
          float4 e0 = *(const float4*)(edge_features + e * 256 + c);
          float4 e1 = *(const float4*)(edge_features + e * 256 + c + 4);
          v[0] = e0.x; v[1] = e0.y; v[2] = e0.z; v[3] = e0.w;
          v[4] = e1.x; v[5] = e1.y; v[6] = e1.z; v[7] = e1.w;
        }
        u16x8 pk;
#pragma unroll
        for (int j = 0; j < 8; ++j) pk[j] = f2bf(v[j]);
        *(u16x8*)(Asb + r * 128 + ((c8 * 16) ^ ((r & 7) << 4))) = pk;
      }
      // ---- stage B: [kg<8][col<512][8] bf16, linear copy from WkvP ----
      for (int i = tid; i < 4096; i += 512) {
        int kg = i >> 9, col = i & 511;
        uint4 w = *(const uint4*)(WkvP + ((size_t)((kc * 8 + kg) * 1024 + p * 512 + col)) * 8);
        *(uint4*)(Bsb + (kg * 512 + col) * 16) = w;
      }
      __syncthreads();
      // ---- fragments + 40 MFMA ----
      bf16x8 af[5][2], bfr[4][2];
#pragma unroll
      for (int fm = 0; fm < 5; ++fm)
#pragma unroll
        for (int ks = 0; ks < 2; ++ks) {
          int row = fm * 16 + lr;
          af[fm][ks] = *(const bf16x8*)(Asb + row * 128 +
                                        (((ks * 64) + (lg << 4)) ^ ((row & 7) << 4)));
        }
#pragma unroll
      for (int fn = 0; fn < 4; ++fn)
#pragma unroll
        for (int ks = 0; ks < 2; ++ks) {
          int col = wid * 64 + fn * 16 + lr;
          int kg = ks * 4 + lg;
          bfr[fn][ks] = *(const bf16x8*)(Bsb + (kg * 512 + col) * 16);
        }
#pragma unroll
      for (int ks = 0; ks < 2; ++ks)
#pragma unroll
        for (int fm = 0; fm < 5; ++fm)
#pragma unroll
          for (int fn = 0; fn < 4; ++fn)
            acc[fm][fn] = __builtin_amdgcn_mfma_f32_16x16x32_bf16(
                af[fm][ks], bfr[fn][ks], acc[fm][fn], 0, 0, 0);
    }
    __syncthreads();
    // ---- dump acc -> bf16 [RR][516] ----
#pragma unroll
    for (int fm = 0; fm < 5; ++fm)
#pragma unroll
      for (int fn = 0; fn < 4; ++fn)
#pragma unroll
        for (int j = 0; j < 4; ++j) {
          int row = fm * 16 + lg * 4 + j;
          int col = wid * 64 + fn * 16 + lr;
          u.dump[row * 516 + col] = f2bf(acc[fm][fn][j]);
        }
    __syncthreads();
    if (p == 0) {
      if (tid < 2 * RR) {
        int h = tid / RR, r = tid % RR;
        int b = r / KN;
        const int c0 = h * 256;
        float s = 0.f;
        for (int c = 0; c < 256; ++c)
          s += q_lds[b][c0 + c] * bf2f(u.dump[r * 516 + c0 + c]);
        s *= 0.0625f;                      // 1/sqrt(dh)
        if (nbr_s[r] == 0) s = -1e10f;     // mask semantics: neighbor id 0
        scores[h][r] = s;
      }
      __syncthreads();
      if (tid < 2 * TB) {
        int h = tid >> 2, b = tid & 3;
        float m = -3.4e38f;
        for (int kk = 0; kk < KN; ++kk) m = fmaxf(m, scores[h][b * KN + kk]);
        float sum = 0.f;
        for (int kk = 0; kk < KN; ++kk) {
          float e = __expf(scores[h][b * KN + kk] - m);
          attnw[h][b * KN + kk] = e;
          sum += e;
        }
        float inv = 1.f / sum;
        for (int kk = 0; kk < KN; ++kk) attnw[h][b * KN + kk] *= inv;
      }
      // next phase's loop-top barrier orders dump readers vs restage
    } else {
      for (int o = tid; o < TB * 512; o += 512) {
        int b = o >> 9, c = o & 511;
        int h = c >> 8;
        float s = 0.f;
#pragma unroll
        for (int kk = 0; kk < KN; ++kk)
          s += attnw[h][b * KN + kk] * bf2f(u.dump[(b * KN + kk) * 516 + c]);
        if (invalid_s[b]) s = 0.f;
        ctx_ws[(size_t)(gb0 + b) * 512 + c] = s;
      }
    }
  }
}

// --------------------------- merge MLP -------------------------------------
// out = relu(ctx @ WoW1 + srcf @ W1[512:768] + b1) @ W2 + b2
__global__ __launch_bounds__(256) void k_mlp(
    const float* __restrict__ ctx_ws, const float* __restrict__ srcf_ws,
    const float* __restrict__ WoW1, const float* __restrict__ W1,
    const float* __restrict__ b1, const float* __restrict__ W2,
    const float* __restrict__ b2, float* __restrict__ out) {
  __shared__ float cx[8][512];
  __shared__ float sf[8][256];
  __shared__ float hh[8][256];
  const int tid = threadIdx.x;
  const int r0 = blockIdx.x * 8;
  for (int i = tid; i < 8 * 128; i += 256) {
    int r = i >> 7, c4 = (i & 127) << 2;
    *(float4*)(&cx[r][c4]) = *(const float4*)(ctx_ws + (size_t)(r0 + r) * 512 + c4);
  }
  for (int i = tid; i < 8 * 64; i += 256) {
    int r = i >> 6, c4 = (i & 63) << 2;
    *(float4*)(&sf[r][c4]) = *(const float4*)(srcf_ws + (size_t)(r0 + r) * 256 + c4);
  }
  __syncthreads();
  const int r = tid >> 5, jb = (tid & 31) << 3;  // 8 outputs each
  {
    float acc[8];
#pragma unroll
    for (int j = 0; j < 8; ++j) acc[j] = b1[jb + j];
    for (int c = 0; c < 512; ++c) {
      float s = cx[r][c];
      float4 w0 = *(const float4*)(WoW1 + c * 256 + jb);
      float4 w1 = *(const float4*)(WoW1 + c * 256 + jb + 4);
      acc[0] += s * w0.x; acc[1] += s * w0.y; acc[2] += s * w0.z; acc[3] += s * w0.w;
      acc[4] += s * w1.x; acc[5] += s * w1.y; acc[6] += s * w1.z; acc[7] += s * w1.w;
    }
    for (int c = 0; c < 256; ++c) {
      float s = sf[r][c];
      float4 w0 = *(const float4*)(W1 + (512 + c) * 256 + jb);
      float4 w1 = *(const float4*)(W1 + (512 + c) * 256 + jb + 4);
      acc[0] += s * w0.x; acc[1] += s * w0.y; acc[2] += s * w0.z; acc[3] += s * w0.w;
      acc[4] += s * w1.x; acc[5] += s * w1.y; acc[6] += s * w1.z; acc[7] += s * w1.w;
    }
#pragma unroll
    for (int j = 0; j < 8; ++j) hh[r][jb + j] = fmaxf(acc[j], 0.f);
  }
  __syncthreads();
  {
    float acc[8];
#pragma unroll
    for (int j = 0; j < 8; ++j) acc[j] = b2[jb + j];
    for (int c = 0; c < 256; ++c) {
      float s = hh[r][c];
      float4 w0 = *(const float4*)(W2 + c * 256 + jb);
      float4 w1 = *(const float4*)(W2 + c * 256 + jb + 4);
      acc[0] += s * w0.x; acc[1] += s * w0.y; acc[2] += s * w0.z; acc[3] += s * w0.w;
      acc[4] += s * w1.x; acc[5] += s * w1.y; acc[6] += s * w1.z; acc[7] += s * w1.w;
    }
    *(float4*)(out + (size_t)(r0 + r) * 256 + jb) = make_float4(acc[0], acc[1], acc[2], acc[3]);
    *(float4*)(out + (size_t)(r0 + r) * 256 + jb + 4) = make_float4(acc[4], acc[5], acc[6], acc[7]);
  }
}

// ---------------------------------------------------------------------------

extern "C" void kernel_launch(void* const* d_in, const int* in_sizes, int n_in,
                              void* d_out, int out_size, void* d_ws, size_t ws_size,
                              hipStream_t stream) {
  const int*   src_nodes     = (const int*)d_in[0];
  const float* timestamps    = (const float*)d_in[1];
  const int*   neighbors     = (const int*)d_in[2];
  const int*   edge_idxs     = (const int*)d_in[3];
  const float* edge_times    = (const float*)d_in[4];
  const float* memory        = (const float*)d_in[5];
  const float* node_table    = (const float*)d_in[6];
  const float* edge_features = (const float*)d_in[7];
  const float* time_w        = (const float*)d_in[8];
  const float* time_b        = (const float*)d_in[9];
  const float* Wq            = (const float*)d_in[10];
  const float* Wk            = (const float*)d_in[11];
  const float* Wv            = (const float*)d_in[12];
  const float* Wo            = (const float*)d_in[13];
  const float* W1            = (const float*)d_in[14];
  const float* b1            = (const float*)d_in[15];
  const float* W2            = (const float*)d_in[16];
  const float* b2            = (const float*)d_in[17];

  char* ws = (char*)d_ws;
  unsigned short* WkvP = (unsigned short*)(ws + 0);         // 1,572,864 B
  float* WoW1    = (float*)(ws + 1572864);                  //   524,288 B
  float* srcq    = (float*)(ws + 2097152);                  //     2,048 B
  float* q_ws    = (float*)(ws + 2099200);                  // 16,777,216 B
  float* srcf_ws = (float*)(ws + 18876416);                 //  8,388,608 B
  float* ctx_ws  = (float*)(ws + 27265024);                 // 16,777,216 B (ends 44,042,240)

  k_pack_wkv<<<3072, 256, 0, stream>>>(Wk, Wv, WkvP);
  k_wow1<<<512, 256, 0, stream>>>(Wo, W1, WoW1);
  k_srcq<<<2, 256, 0, stream>>>(time_b, Wq, srcq);
  k_qproj<<<1024, 256, 0, stream>>>(src_nodes, memory, node_table, Wq, srcq, q_ws, srcf_ws);
  k_attn<<<2048, 512, 0, stream>>>(neighbors, edge_idxs, edge_times, timestamps,
                                   memory, node_table, edge_features, time_w, time_b,
                                   WkvP, q_ws, ctx_ws);
  k_mlp<<<1024, 256, 0, stream>>>(ctx_ws, srcf_ws, WoW1, W1, b1, W2, b2, (float*)d_out);
}